// Round 2
// baseline (184.472 us; speedup 1.0000x reference)
//
#include <hip/hip_runtime.h>

// get_LL_mnist: 2-level Haar DWT (db1, zero) + zeroed details + 2-level
// inverse == 4x4 block mean, broadcast back. [32768,1,28,28] fp32.
//
// R2 design: fully-coalesced streaming. Each 256-thread block owns 16 images
// = 3136 float4 viewed flat. Phase 1: lane-linear float4 loads (1 KB per wave
// instruction, zero scatter), horizontal sum -> LDS P[f] (one float per input
// float4 == per (row, col-group)). Phase 2: each output float4 (row r, col
// group cg) needs the 4 row-partials of its 4x4 block: P[img*196 + rg*28 + cg
// + {0,7,14,21}]; reads are same-address broadcasts across the 4 rows of a
// group (free), stores are lane-linear coalesced.
//
// Grid 2048 blocks x 256 -> 8 blocks/CU, full 32 waves/CU occupancy.

__global__ __launch_bounds__(256) void haar_ll2_stream(
    const float* __restrict__ in, float* __restrict__ out) {
    __shared__ float P[3136];            // 16 images * 196 row-partials
    const int tid = threadIdx.x;
    const size_t base = (size_t)blockIdx.x * 3136;  // float4 units
    const float4* __restrict__ in4  = reinterpret_cast<const float4*>(in)  + base;
    float4*       __restrict__ out4 = reinterpret_cast<float4*>(out) + base;

    // Phase 1: coalesced load + horizontal reduce. 3136 = 12*256 + 64.
    #pragma unroll
    for (int k = 0; k < 13; ++k) {
        int f = tid + (k << 8);
        if (f < 3136) {
            float4 v = in4[f];
            P[f] = (v.x + v.y) + (v.z + v.w);
        }
    }
    __syncthreads();

    // Phase 2: gather 4 row-partials per 4x4 block, coalesced store.
    #pragma unroll
    for (int k = 0; k < 13; ++k) {
        int f = tid + (k << 8);
        if (f < 3136) {
            int img = f / 196;            // const-div -> magic mul
            int rem = f - img * 196;      // 0..195 = r*7 + cg
            int r   = rem / 7;
            int cg  = rem - r * 7;
            int rg  = r >> 2;             // row group 0..6
            int a   = img * 196 + rg * 28 + cg;
            float s = ((P[a] + P[a + 7]) + (P[a + 14] + P[a + 21])) * 0.0625f;
            out4[f] = make_float4(s, s, s, s);
        }
    }
}

extern "C" void kernel_launch(void* const* d_in, const int* in_sizes, int n_in,
                              void* d_out, int out_size, void* d_ws, size_t ws_size,
                              hipStream_t stream) {
    const float* in  = (const float*)d_in[0];
    float*       out = (float*)d_out;
    // lev (d_in[1]) is static == 2; kernel hardcodes the collapsed form.
    // 32768 images / 16 per block = 2048 blocks.
    int nblocks = (in_sizes[0] / 784) / 16;
    haar_ll2_stream<<<nblocks, 256, 0, stream>>>(in, out);
}

// Round 4
// 181.717 us; speedup vs baseline: 1.0152x; 1.0152x over previous
//
#include <hip/hip_runtime.h>

// get_LL_mnist: 2-level Haar DWT (db1, zero) + zeroed details + 2-level
// inverse == 4x4 block mean, broadcast back. [32768,1,28,28] fp32.
//
// R3 (resubmit after GPU acquisition timeout): R1/R2 showed access pattern is
// irrelevant (both ~2.4 TB/s, 62-66 us). Remaining levers: (a) HBM read bytes
// — input+output ~196 MB slightly overflows the 256 MB L3, so output
// write-allocation evicts the warm input (FETCH was 50 MB, not 0).
// Non-temporal loads+stores (nt hint) keep the read-once input / write-once
// output at low L3 retention priority. (b) thread-level pipelining: 2 blocks
// per thread, all 8 loads issued before any store (no LDS, no barrier).

typedef float f4 __attribute__((ext_vector_type(4)));

__global__ __launch_bounds__(256) void haar_ll2_nt(
    const float* __restrict__ in, float* __restrict__ out, int half) {
    int t = blockIdx.x * 256 + threadIdx.x;
    if (t >= half) return;

    const f4* __restrict__ in4  = reinterpret_cast<const f4*>(in);
    f4*       __restrict__ out4 = reinterpret_cast<f4*>(out);

    // Block indices: t and t+half (same intra-wave pattern as R1 per access).
    int p0, p1;
    {
        int b = t;
        int img = b / 49, rem = b - img * 49;
        int rg = rem / 7, cg = rem - rg * 7;
        p0 = img * 196 + rg * 28 + cg;
    }
    {
        int b = t + half;
        int img = b / 49, rem = b - img * 49;
        int rg = rem / 7, cg = rem - rg * 7;
        p1 = img * 196 + rg * 28 + cg;
    }

    // Issue all 8 non-temporal loads before any use.
    f4 a0 = __builtin_nontemporal_load(in4 + p0);
    f4 b0 = __builtin_nontemporal_load(in4 + p0 + 7);
    f4 c0 = __builtin_nontemporal_load(in4 + p0 + 14);
    f4 d0 = __builtin_nontemporal_load(in4 + p0 + 21);
    f4 a1 = __builtin_nontemporal_load(in4 + p1);
    f4 b1 = __builtin_nontemporal_load(in4 + p1 + 7);
    f4 c1 = __builtin_nontemporal_load(in4 + p1 + 14);
    f4 d1 = __builtin_nontemporal_load(in4 + p1 + 21);

    float s0 = ((a0.x + a0.y) + (a0.z + a0.w)) + ((b0.x + b0.y) + (b0.z + b0.w)) +
               ((c0.x + c0.y) + (c0.z + c0.w)) + ((d0.x + d0.y) + (d0.z + d0.w));
    float s1 = ((a1.x + a1.y) + (a1.z + a1.w)) + ((b1.x + b1.y) + (b1.z + b1.w)) +
               ((c1.x + c1.y) + (c1.z + c1.w)) + ((d1.x + d1.y) + (d1.z + d1.w));
    s0 *= 0.0625f;
    s1 *= 0.0625f;

    f4 v0 = {s0, s0, s0, s0};
    f4 v1 = {s1, s1, s1, s1};
    __builtin_nontemporal_store(v0, out4 + p0);
    __builtin_nontemporal_store(v0, out4 + p0 + 7);
    __builtin_nontemporal_store(v0, out4 + p0 + 14);
    __builtin_nontemporal_store(v0, out4 + p0 + 21);
    __builtin_nontemporal_store(v1, out4 + p1);
    __builtin_nontemporal_store(v1, out4 + p1 + 7);
    __builtin_nontemporal_store(v1, out4 + p1 + 14);
    __builtin_nontemporal_store(v1, out4 + p1 + 21);
}

extern "C" void kernel_launch(void* const* d_in, const int* in_sizes, int n_in,
                              void* d_out, int out_size, void* d_ws, size_t ws_size,
                              hipStream_t stream) {
    const float* in  = (const float*)d_in[0];
    float*       out = (float*)d_out;
    // lev (d_in[1]) is static == 2; collapsed form hardcoded.
    int total = in_sizes[0] / 16;   // 4x4 blocks
    int half  = total / 2;          // 2 blocks per thread
    int nblocks = (half + 255) / 256;
    haar_ll2_nt<<<nblocks, 256, 0, stream>>>(in, out, half);
}

// Round 7
// 176.812 us; speedup vs baseline: 1.0433x; 1.0277x over previous
//
#include <hip/hip_runtime.h>

// get_LL_mnist: 2-level Haar DWT (db1, zero) + zeroed details + 2-level
// inverse == 4x4 block mean, broadcast back. [32768,1,28,28] fp32.
//
// R5 (2nd resubmit; GPU acquisition timeouts): split into two pure-direction
// streaming kernels (mixed read/write in one kernel plateaued at ~3.3 TB/s
// across R1-R3, while the harness's own pure-write fills hit 6.7 TB/s in the
// same windows):
//   K1 (reduce):  read input 98 MB (nt), write LL plane 6.4 MB to d_ws
//                 (cached stores -> stays in L2/L3 for K2).
//   K2 (bcast):   read LL 6.4 MB (cache-hot), pure nt write-stream 98 MB.
// Same-stream kernel ordering guarantees K2 sees K1's ws writes.

typedef float f4 __attribute__((ext_vector_type(4)));

// One thread = two 4x4 block sums (t and t+half) for deeper load MLP.
__global__ __launch_bounds__(256) void haar_ll2_reduce(
    const float* __restrict__ in, float* __restrict__ ll, int half) {
    int t = blockIdx.x * 256 + threadIdx.x;
    if (t >= half) return;
    const f4* __restrict__ in4 = reinterpret_cast<const f4*>(in);

    int b0 = t, b1 = t + half;
    int img0 = b0 / 49, rem0 = b0 - img0 * 49;
    int rg0 = rem0 / 7,  cg0 = rem0 - rg0 * 7;
    int p0 = img0 * 196 + rg0 * 28 + cg0;
    int img1 = b1 / 49, rem1 = b1 - img1 * 49;
    int rg1 = rem1 / 7,  cg1 = rem1 - rg1 * 7;
    int p1 = img1 * 196 + rg1 * 28 + cg1;

    // 8 loads in flight before any use.
    f4 a0 = __builtin_nontemporal_load(in4 + p0);
    f4 b0v = __builtin_nontemporal_load(in4 + p0 + 7);
    f4 c0 = __builtin_nontemporal_load(in4 + p0 + 14);
    f4 d0 = __builtin_nontemporal_load(in4 + p0 + 21);
    f4 a1 = __builtin_nontemporal_load(in4 + p1);
    f4 b1v = __builtin_nontemporal_load(in4 + p1 + 7);
    f4 c1 = __builtin_nontemporal_load(in4 + p1 + 14);
    f4 d1 = __builtin_nontemporal_load(in4 + p1 + 21);

    float s0 = ((a0.x + a0.y) + (a0.z + a0.w)) + ((b0v.x + b0v.y) + (b0v.z + b0v.w)) +
               ((c0.x + c0.y) + (c0.z + c0.w)) + ((d0.x + d0.y) + (d0.z + d0.w));
    float s1 = ((a1.x + a1.y) + (a1.z + a1.w)) + ((b1v.x + b1v.y) + (b1v.z + b1v.w)) +
               ((c1.x + c1.y) + (c1.z + c1.w)) + ((d1.x + d1.y) + (d1.z + d1.w));
    // Cached stores: LL plane (6.4 MB) should stay resident for K2.
    ll[b0] = s0 * 0.0625f;
    ll[b1] = s1 * 0.0625f;
}

// One thread = two output float4s (t and t+half). Each output float4 is a
// single broadcast LL value (blocks are 4-wide aligned).
__global__ __launch_bounds__(256) void haar_ll2_bcast(
    const float* __restrict__ ll, float* __restrict__ out, int half) {
    int t = blockIdx.x * 256 + threadIdx.x;
    if (t >= half) return;
    f4* __restrict__ out4 = reinterpret_cast<f4*>(out);

    int f0 = t, f1 = t + half;
    int img0 = f0 / 196, rem0 = f0 - img0 * 196;
    int r0 = rem0 / 7,   cg0 = rem0 - r0 * 7;
    float s0 = ll[img0 * 49 + (r0 >> 2) * 7 + cg0];
    int img1 = f1 / 196, rem1 = f1 - img1 * 196;
    int r1 = rem1 / 7,   cg1 = rem1 - r1 * 7;
    float s1 = ll[img1 * 49 + (r1 >> 2) * 7 + cg1];

    f4 v0 = {s0, s0, s0, s0};
    f4 v1 = {s1, s1, s1, s1};
    __builtin_nontemporal_store(v0, out4 + f0);
    __builtin_nontemporal_store(v1, out4 + f1);
}

extern "C" void kernel_launch(void* const* d_in, const int* in_sizes, int n_in,
                              void* d_out, int out_size, void* d_ws, size_t ws_size,
                              hipStream_t stream) {
    const float* in  = (const float*)d_in[0];
    float*       out = (float*)d_out;
    float*       ll  = (float*)d_ws;     // 32768*49 floats = 6.4 MB scratch
    // lev (d_in[1]) is static == 2; collapsed form hardcoded.

    int total_blocks = in_sizes[0] / 16;         // 4x4 blocks = 1605632
    int h1 = total_blocks / 2;                   // 2 sums per thread
    haar_ll2_reduce<<<(h1 + 255) / 256, 256, 0, stream>>>(in, ll, h1);

    int total_f4 = in_sizes[0] / 4;              // output float4 count
    int h2 = total_f4 / 2;                       // 2 stores per thread
    haar_ll2_bcast<<<(h2 + 255) / 256, 256, 0, stream>>>(ll, out, h2);
}